// Round 6
// baseline (124.366 us; speedup 1.0000x reference)
//
#include <hip/hip_runtime.h>

// ---------------------------------------------------------------------------
// LaplaceKAN layer as a fused-feature bf16 MFMA GEMM.
//   y[b,o] = sum_{i,g} exp(-x[b,i]*lam_g)*C[0,o,i,g] + exp(+x[b,i]*lam_g)*C[1,o,i,g] + bias[o]
//   lam_g = 0.1 + 0.06*g, g in [0,16)
// GEMM view: M=4096, N=256, K=8192 (k = s*4096 + i*16 + g).
//
// Session model (rounds 0-5): timed region carries ~82-84 us of fixed harness
// workspace-poison fills (2 x 256 MiB at ~6.5 TB/s); our kernels total ~8 us.
// The R0 GEMM schedule (2-barrier, single-buffered tiles) is within ~2 us of
// its pipe floor -- every rescheduling attempt was sub-noise or regressed.
// This version keeps R0's GEMM body BYTE-IDENTICAL and cuts the remaining
// kernel-side cost structurally: atomic epilogue (MODE 1) deletes the 32 MiB
// split-K P round-trip AND the reduce_bias dispatch; Out (4 MiB, L2-resident)
// is zeroed via hipMemsetAsync and accumulated with f32 atomics (+bias at kt==0).
// Tiling: BM=128, BN=128, BK=64, 256 threads (2x2 waves of 64x64), SPLITK=8
// -> 512 blocks = 2 blocks/CU.
// ---------------------------------------------------------------------------

typedef __bf16 bf16x8 __attribute__((ext_vector_type(8)));
typedef __bf16 bf16x4 __attribute__((ext_vector_type(4)));
typedef float  f32x4  __attribute__((ext_vector_type(4)));

#define M_TOT 4096
#define N_TOT 256
#define MN_TOT (M_TOT * N_TOT)
#define SPLITK 8

__device__ __forceinline__ void gload_lds16(const __bf16* g, __bf16* l) {
  // async 16B/lane global->LDS; LDS dest = wave-uniform base + lane*16
  __builtin_amdgcn_global_load_lds(
      (const __attribute__((address_space(1))) void*)g,
      (__attribute__((address_space(3))) void*)l, 16, 0, 0);
}

// fp32 coeffs (2,O,I,G) -> bf16 Wb[o][k], k = s*4096 + i*16 + g.
// Both sides contiguous over x=(i*16+g) for fixed (s,o): pure chunk copy+cvt.
__global__ void convert_w(const float* __restrict__ C, __bf16* __restrict__ W) {
  int t = blockIdx.x * 256 + threadIdx.x;      // 524288 threads, 4 elems each
  int E = t << 2;
  int c = E >> 12, x4 = E & 4095;              // c = s*256+o
  int s = c >> 8, o = c & 255;
  const f32x4 v = *(const f32x4*)(C + (size_t)c * 4096 + x4);
  bf16x4 w;
  w[0] = (__bf16)v[0]; w[1] = (__bf16)v[1]; w[2] = (__bf16)v[2]; w[3] = (__bf16)v[3];
  *(bf16x4*)(W + (size_t)o * 8192 + (size_t)s * 4096 + x4) = w;
}

// MODE 0: write split-K partials to P.  MODE 1: atomicAdd into Out (+bias at kt==0).
template <int MODE>
__global__ __launch_bounds__(256, 2)
void laplace_gemm(const float* __restrict__ X, const __bf16* __restrict__ Wb,
                  const float* __restrict__ Bias, float* __restrict__ Out,
                  float* __restrict__ P) {
  // A tile padded to 72 elem/row (144B: 16B-aligned, bank-balanced reads/writes)
  __shared__ __bf16 As[128 * 72];
  // B tile 128x64, rows 128B; 16B chunks XOR-swizzled by (row&7) for bank spread
  __shared__ __bf16 Bs[128 * 64];

  const int tid = threadIdx.x;
  const int mt = blockIdx.x, nt = blockIdx.y, kt = blockIdx.z;
  const int m0 = mt * 128, n0 = nt * 128;
  const int s   = kt >> 2;          // sign half: 0 -> exp(-e), 1 -> exp(+e)
  const int i0c = (kt & 3) * 64;    // i-range of this K-chunk (64 i values)

  const int wv = tid >> 6, lane = tid & 63;
  const int wm = wv & 1, wn = wv >> 1;    // 2x2 wave grid, each 64x64
  const int lm = lane & 15, q = lane >> 4;

  // feature-gen assignment: thread handles two (row, i-sub) pairs per iter
  const int mr0 = tid >> 2,         ii0 = tid & 3;
  const int mr1 = (256 + tid) >> 2, ii1 = tid & 3;   // (256+tid)&3 == tid&3
  const float* xp0 = X + (size_t)(m0 + mr0) * 256 + i0c + ii0;
  const float* xp1 = X + (size_t)(m0 + mr1) * 256 + i0c + ii1;

  const float sgn = s ? 1.0f : -1.0f;
  const float c0 = 0.1f * sgn, cd = 0.06f * sgn;

  const f32x4 zero = {0.f, 0.f, 0.f, 0.f};
  f32x4 acc[4][4];
#pragma unroll
  for (int a = 0; a < 4; ++a)
#pragma unroll
    for (int b = 0; b < 4; ++b) acc[a][b] = zero;

  // element offset of this K-chunk within a Wb row
  const size_t wrow = (size_t)s * 4096 + (size_t)i0c * 16;

  float xc0 = *xp0, xc1 = *xp1;

  for (int j = 0; j < 16; ++j) {   // 16 x BK=64 -> K-chunk 1024
    // ---- async stage B tile (4 x 16B per thread) ----
    const size_t kw = wrow + (size_t)j * 64;
#pragma unroll
    for (int qq = 0; qq < 4; ++qq) {
      const int idx = qq * 256 + tid;
      const int r = idx >> 3, cc = idx & 7;
      const __bf16* gsrc = Wb + (size_t)(n0 + r) * 8192 + kw + ((cc ^ (r & 7)) << 3);
      __bf16* ldst = Bs + ((qq * 256 + (tid & ~63)) << 3);  // wave-uniform base
      gload_lds16(gsrc, ldst);
    }

    // prefetch next iter's x while loads are in flight
    float xn0 = 0.f, xn1 = 0.f;
    if (j < 15) { xn0 = xp0[4 * (j + 1)]; xn1 = xp1[4 * (j + 1)]; }

    // ---- generate A features: f_g = p * r^g ----
    {
      const float p0 = __expf(c0 * xc0), rr = __expf(cd * xc0);
      bf16x8 v0, v1; float f = p0;
#pragma unroll
      for (int h = 0; h < 8; ++h) { v0[h] = (__bf16)f; f *= rr; }
#pragma unroll
      for (int h = 0; h < 8; ++h) { v1[h] = (__bf16)f; f *= rr; }
      *(bf16x8*)&As[mr0 * 72 + ii0 * 16]     = v0;
      *(bf16x8*)&As[mr0 * 72 + ii0 * 16 + 8] = v1;
    }
    {
      const float p0 = __expf(c0 * xc1), rr = __expf(cd * xc1);
      bf16x8 v0, v1; float f = p0;
#pragma unroll
      for (int h = 0; h < 8; ++h) { v0[h] = (__bf16)f; f *= rr; }
#pragma unroll
      for (int h = 0; h < 8; ++h) { v1[h] = (__bf16)f; f *= rr; }
      *(bf16x8*)&As[mr1 * 72 + ii1 * 16]     = v0;
      *(bf16x8*)&As[mr1 * 72 + ii1 * 16 + 8] = v1;
    }

    __syncthreads();   // drains vmcnt (B tile) + lgkm (A writes)

    // ---- MFMA: 2 k-steps x 4x4 frags ----
#pragma unroll
    for (int kk = 0; kk < 2; ++kk) {
      bf16x8 af[4], bf[4];
#pragma unroll
      for (int a = 0; a < 4; ++a)
        af[a] = *(const bf16x8*)&As[(wm * 64 + a * 16 + lm) * 72 + kk * 32 + q * 8];
      const int pc8 = (((kk << 2) + q) ^ (lm & 7)) << 3;  // un-swizzle B chunk
#pragma unroll
      for (int b = 0; b < 4; ++b)
        bf[b] = *(const bf16x8*)&Bs[(wn * 64 + b * 16 + lm) * 64 + pc8];
#pragma unroll
      for (int a = 0; a < 4; ++a)
#pragma unroll
        for (int b = 0; b < 4; ++b)
          acc[a][b] = __builtin_amdgcn_mfma_f32_16x16x32_bf16(af[a], bf[b], acc[a][b], 0, 0, 0);
    }
    __syncthreads();   // before next iter overwrites tiles

    xc0 = xn0; xc1 = xn1;
  }

  // ---- epilogue: D[row=q*4+reg][col=lm] (m89-verified C/D layout) ----
  if constexpr (MODE == 0) {
    float* Pk = P + (size_t)kt * MN_TOT;
#pragma unroll
    for (int a = 0; a < 4; ++a) {
      const int mrow = m0 + wm * 64 + a * 16 + q * 4;
#pragma unroll
      for (int rr = 0; rr < 4; ++rr)
#pragma unroll
        for (int b = 0; b < 4; ++b) {
          const int n = n0 + wn * 64 + b * 16 + lm;
          Pk[(size_t)(mrow + rr) * 256 + n] = acc[a][b][rr];
        }
    }
  } else {
#pragma unroll
    for (int a = 0; a < 4; ++a) {
      const int mrow = m0 + wm * 64 + a * 16 + q * 4;
#pragma unroll
      for (int rr = 0; rr < 4; ++rr)
#pragma unroll
        for (int b = 0; b < 4; ++b) {
          const int n = n0 + wn * 64 + b * 16 + lm;
          float v = acc[a][b][rr];
          if (kt == 0) v += Bias[n];
          atomicAdd(&Out[(size_t)(mrow + rr) * 256 + n], v);
        }
    }
  }
}

// sum 8 split-K partials + bias -> out (fallback path only)
__global__ void reduce_bias(const float* __restrict__ P, const float* __restrict__ Bias,
                            float* __restrict__ Out) {
  const int t = blockIdx.x * 256 + threadIdx.x;
  const size_t base = (size_t)t * 4;
  f32x4 sv = *(const f32x4*)&P[base];
#pragma unroll
  for (int k = 1; k < SPLITK; ++k) sv += *(const f32x4*)&P[(size_t)k * MN_TOT + base];
  sv += *(const f32x4*)&Bias[base & 255];
  *(f32x4*)&Out[base] = sv;
}

extern "C" void kernel_launch(void* const* d_in, const int* in_sizes, int n_in,
                              void* d_out, int out_size, void* d_ws, size_t ws_size,
                              hipStream_t stream) {
  const float* X    = (const float*)d_in[0];
  const float* C    = (const float*)d_in[1];
  const float* Bias = (const float*)d_in[2];
  float* Out = (float*)d_out;

  __bf16* Wb = (__bf16*)d_ws;
  const size_t wb_bytes = (size_t)N_TOT * 8192 * sizeof(__bf16);   // 4 MiB
  float* P = (float*)((char*)d_ws + wb_bytes);                     // unused in MODE 1

  convert_w<<<2048, 256, 0, stream>>>(C, Wb);

  // Atomic epilogue: zero Out (4 MiB, ~0.6 us), accumulate all split-K
  // partials directly -- deletes the 32 MiB P round-trip and the reduce
  // dispatch entirely.
  hipMemsetAsync(d_out, 0, (size_t)out_size * sizeof(float), stream);
  laplace_gemm<1><<<dim3(32, 2, SPLITK), 256, 0, stream>>>(X, Wb, Bias, Out, P);
}

// Round 7
// 120.930 us; speedup vs baseline: 1.0284x; 1.0284x over previous
//
#include <hip/hip_runtime.h>

// ---------------------------------------------------------------------------
// LaplaceKAN layer as a fused-feature bf16 MFMA GEMM.
//   y[b,o] = sum_{i,g} exp(-x[b,i]*lam_g)*C[0,o,i,g] + exp(+x[b,i]*lam_g)*C[1,o,i,g] + bias[o]
//   lam_g = 0.1 + 0.06*g, g in [0,16)
// GEMM view: M=4096, N=256, K=8192 (k = s*4096 + i*16 + g).
//
// Session model (R0-R6, pinned by R6's direct GEMM measurement):
//   timed region = ~41.5us ws-poison fill + ~7us PER DISPATCH GAP + kernels
//   (convert 1.5, GEMM ~13 @ tau=0.8us/iter, reduce 5.5). Atomic epilogue
//   (R6) = +48us of cross-XCD line ping-pong -- reverted.
// This version deletes the reduce DISPATCH (not its work): last-arriving
// kt-block per (mt,nt) tile reduces the 8 split-K partials via a ticket
// (device-scope atomicAdd + __threadfence, G16-compliant, no spinning).
// Main loop byte-identical to R0's proven 2-barrier schedule.
// Tiling: BM=128, BN=128, BK=64, 256 threads (2x2 waves of 64x64), SPLITK=8
// -> 512 blocks = 2 blocks/CU.
// ---------------------------------------------------------------------------

typedef __bf16 bf16x8 __attribute__((ext_vector_type(8)));
typedef __bf16 bf16x4 __attribute__((ext_vector_type(4)));
typedef float  f32x4  __attribute__((ext_vector_type(4)));

#define M_TOT 4096
#define N_TOT 256
#define MN_TOT (M_TOT * N_TOT)
#define SPLITK 8
#define NTILES 64   // 32 mt x 2 nt

__device__ __forceinline__ void gload_lds16(const __bf16* g, __bf16* l) {
  // async 16B/lane global->LDS; LDS dest = wave-uniform base + lane*16
  __builtin_amdgcn_global_load_lds(
      (const __attribute__((address_space(1))) void*)g,
      (__attribute__((address_space(3))) void*)l, 16, 0, 0);
}

// fp32 coeffs (2,O,I,G) -> bf16 Wb[o][k], k = s*4096 + i*16 + g.
// Also zeroes the per-tile ticket counters (runs before the GEMM in-stream).
__global__ void convert_w(const float* __restrict__ C, __bf16* __restrict__ W,
                          unsigned* __restrict__ Cnt) {
  if (blockIdx.x == 0 && threadIdx.x < NTILES) Cnt[threadIdx.x] = 0u;
  int t = blockIdx.x * 256 + threadIdx.x;      // 524288 threads, 4 elems each
  int E = t << 2;
  int c = E >> 12, x4 = E & 4095;              // c = s*256+o
  int s = c >> 8, o = c & 255;
  const f32x4 v = *(const f32x4*)(C + (size_t)c * 4096 + x4);
  bf16x4 w;
  w[0] = (__bf16)v[0]; w[1] = (__bf16)v[1]; w[2] = (__bf16)v[2]; w[3] = (__bf16)v[3];
  *(bf16x4*)(W + (size_t)o * 8192 + (size_t)s * 4096 + x4) = w;
}

// MODE 0: P-partial + ticket; last block per tile reduces 8 partials + bias.
// MODE 1: fallback atomicAdd into Out (+bias at kt==0), requires pre-zeroed Out.
template <int MODE>
__global__ __launch_bounds__(256, 2)
void laplace_gemm(const float* __restrict__ X, const __bf16* __restrict__ Wb,
                  const float* __restrict__ Bias, float* __restrict__ Out,
                  float* __restrict__ P, unsigned* __restrict__ Cnt) {
  // A tile padded to 72 elem/row (144B: 16B-aligned, bank-balanced reads/writes)
  __shared__ __bf16 As[128 * 72];
  // B tile 128x64, rows 128B; 16B chunks XOR-swizzled by (row&7) for bank spread
  __shared__ __bf16 Bs[128 * 64];

  const int tid = threadIdx.x;
  const int mt = blockIdx.x, nt = blockIdx.y, kt = blockIdx.z;
  const int m0 = mt * 128, n0 = nt * 128;
  const int s   = kt >> 2;          // sign half: 0 -> exp(-e), 1 -> exp(+e)
  const int i0c = (kt & 3) * 64;    // i-range of this K-chunk (64 i values)

  const int wv = tid >> 6, lane = tid & 63;
  const int wm = wv & 1, wn = wv >> 1;    // 2x2 wave grid, each 64x64
  const int lm = lane & 15, q = lane >> 4;

  // feature-gen assignment: thread handles two (row, i-sub) pairs per iter
  const int mr0 = tid >> 2,         ii0 = tid & 3;
  const int mr1 = (256 + tid) >> 2, ii1 = tid & 3;   // (256+tid)&3 == tid&3
  const float* xp0 = X + (size_t)(m0 + mr0) * 256 + i0c + ii0;
  const float* xp1 = X + (size_t)(m0 + mr1) * 256 + i0c + ii1;

  const float sgn = s ? 1.0f : -1.0f;
  const float c0 = 0.1f * sgn, cd = 0.06f * sgn;

  const f32x4 zero = {0.f, 0.f, 0.f, 0.f};
  f32x4 acc[4][4];
#pragma unroll
  for (int a = 0; a < 4; ++a)
#pragma unroll
    for (int b = 0; b < 4; ++b) acc[a][b] = zero;

  // element offset of this K-chunk within a Wb row
  const size_t wrow = (size_t)s * 4096 + (size_t)i0c * 16;

  float xc0 = *xp0, xc1 = *xp1;

  for (int j = 0; j < 16; ++j) {   // 16 x BK=64 -> K-chunk 1024
    // ---- async stage B tile (4 x 16B per thread) ----
    const size_t kw = wrow + (size_t)j * 64;
#pragma unroll
    for (int qq = 0; qq < 4; ++qq) {
      const int idx = qq * 256 + tid;
      const int r = idx >> 3, cc = idx & 7;
      const __bf16* gsrc = Wb + (size_t)(n0 + r) * 8192 + kw + ((cc ^ (r & 7)) << 3);
      __bf16* ldst = Bs + ((qq * 256 + (tid & ~63)) << 3);  // wave-uniform base
      gload_lds16(gsrc, ldst);
    }

    // prefetch next iter's x while loads are in flight
    float xn0 = 0.f, xn1 = 0.f;
    if (j < 15) { xn0 = xp0[4 * (j + 1)]; xn1 = xp1[4 * (j + 1)]; }

    // ---- generate A features: f_g = p * r^g ----
    {
      const float p0 = __expf(c0 * xc0), rr = __expf(cd * xc0);
      bf16x8 v0, v1; float f = p0;
#pragma unroll
      for (int h = 0; h < 8; ++h) { v0[h] = (__bf16)f; f *= rr; }
#pragma unroll
      for (int h = 0; h < 8; ++h) { v1[h] = (__bf16)f; f *= rr; }
      *(bf16x8*)&As[mr0 * 72 + ii0 * 16]     = v0;
      *(bf16x8*)&As[mr0 * 72 + ii0 * 16 + 8] = v1;
    }
    {
      const float p0 = __expf(c0 * xc1), rr = __expf(cd * xc1);
      bf16x8 v0, v1; float f = p0;
#pragma unroll
      for (int h = 0; h < 8; ++h) { v0[h] = (__bf16)f; f *= rr; }
#pragma unroll
      for (int h = 0; h < 8; ++h) { v1[h] = (__bf16)f; f *= rr; }
      *(bf16x8*)&As[mr1 * 72 + ii1 * 16]     = v0;
      *(bf16x8*)&As[mr1 * 72 + ii1 * 16 + 8] = v1;
    }

    __syncthreads();   // drains vmcnt (B tile) + lgkm (A writes)

    // ---- MFMA: 2 k-steps x 4x4 frags ----
#pragma unroll
    for (int kk = 0; kk < 2; ++kk) {
      bf16x8 af[4], bf[4];
#pragma unroll
      for (int a = 0; a < 4; ++a)
        af[a] = *(const bf16x8*)&As[(wm * 64 + a * 16 + lm) * 72 + kk * 32 + q * 8];
      const int pc8 = (((kk << 2) + q) ^ (lm & 7)) << 3;  // un-swizzle B chunk
#pragma unroll
      for (int b = 0; b < 4; ++b)
        bf[b] = *(const bf16x8*)&Bs[(wn * 64 + b * 16 + lm) * 64 + pc8];
#pragma unroll
      for (int a = 0; a < 4; ++a)
#pragma unroll
        for (int b = 0; b < 4; ++b)
          acc[a][b] = __builtin_amdgcn_mfma_f32_16x16x32_bf16(af[a], bf[b], acc[a][b], 0, 0, 0);
    }
    __syncthreads();   // before next iter overwrites tiles

    xc0 = xn0; xc1 = xn1;
  }

  // ---- epilogue: D[row=q*4+reg][col=lm] (m89-verified C/D layout) ----
  if constexpr (MODE == 0) {
    float* Pk = P + (size_t)kt * MN_TOT;
#pragma unroll
    for (int a = 0; a < 4; ++a) {
      const int mrow = m0 + wm * 64 + a * 16 + q * 4;
#pragma unroll
      for (int rr = 0; rr < 4; ++rr)
#pragma unroll
        for (int b = 0; b < 4; ++b) {
          const int n = n0 + wn * 64 + b * 16 + lm;
          Pk[(size_t)(mrow + rr) * 256 + n] = acc[a][b][rr];
        }
    }

    // ---- ticket: last-arriving kt-block for this (mt,nt) reduces ----
    __shared__ unsigned lastS;
    __syncthreads();                 // all P stores issued & drained (vmcnt0)
    if (tid == 0) {
      __threadfence();               // release: P partial device-visible
      const unsigned old = atomicAdd(&Cnt[mt * 2 + nt], 1u);
      lastS = (old == SPLITK - 1) ? 1u : 0u;
    }
    __syncthreads();
    if (lastS) {
      __threadfence();               // acquire: see all 8 partials
#pragma unroll
      for (int u = 0; u < 16; ++u) {
        const int c = tid + 256 * u;           // 4096 f32x4 chunks in tile
        const int row = c >> 5, c4 = (c & 31) << 2;
        const size_t off = (size_t)(m0 + row) * 256 + n0 + c4;
        f32x4 sv = *(const f32x4*)&P[off];
#pragma unroll
        for (int k = 1; k < SPLITK; ++k)
          sv += *(const f32x4*)&P[(size_t)k * MN_TOT + off];
        sv += *(const f32x4*)&Bias[n0 + c4];
        *(f32x4*)&Out[off] = sv;
      }
    }
  } else {
#pragma unroll
    for (int a = 0; a < 4; ++a) {
      const int mrow = m0 + wm * 64 + a * 16 + q * 4;
#pragma unroll
      for (int rr = 0; rr < 4; ++rr)
#pragma unroll
        for (int b = 0; b < 4; ++b) {
          const int n = n0 + wn * 64 + b * 16 + lm;
          float v = acc[a][b][rr];
          if (kt == 0) v += Bias[n];
          atomicAdd(&Out[(size_t)(mrow + rr) * 256 + n], v);
        }
    }
  }
}

extern "C" void kernel_launch(void* const* d_in, const int* in_sizes, int n_in,
                              void* d_out, int out_size, void* d_ws, size_t ws_size,
                              hipStream_t stream) {
  const float* X    = (const float*)d_in[0];
  const float* C    = (const float*)d_in[1];
  const float* Bias = (const float*)d_in[2];
  float* Out = (float*)d_out;

  __bf16* Wb = (__bf16*)d_ws;
  const size_t wb_bytes = (size_t)N_TOT * 8192 * sizeof(__bf16);   // 4 MiB
  const size_t p_bytes  = (size_t)SPLITK * MN_TOT * sizeof(float); // 32 MiB
  float* P = (float*)((char*)d_ws + wb_bytes);
  unsigned* Cnt = (unsigned*)((char*)d_ws + wb_bytes + p_bytes);   // 64 u32

  if (ws_size >= wb_bytes + p_bytes + NTILES * sizeof(unsigned)) {
    convert_w<<<2048, 256, 0, stream>>>(C, Wb, Cnt);
    laplace_gemm<0><<<dim3(32, 2, SPLITK), 256, 0, stream>>>(X, Wb, Bias, Out, P, Cnt);
  } else {
    convert_w<<<2048, 256, 0, stream>>>(C, Wb, Cnt);
    hipMemsetAsync(d_out, 0, (size_t)out_size * sizeof(float), stream);
    laplace_gemm<1><<<dim3(32, 2, SPLITK), 256, 0, stream>>>(X, Wb, Bias, Out, P, Cnt);
  }
}

// Round 8
// 100.230 us; speedup vs baseline: 1.2408x; 1.2065x over previous
//
#include <hip/hip_runtime.h>

// ---------------------------------------------------------------------------
// LaplaceKAN layer as a fused-feature bf16 MFMA GEMM.
//   y[b,o] = sum_{i,g} exp(-x[b,i]*lam_g)*C[0,o,i,g] + exp(+x[b,i]*lam_g)*C[1,o,i,g] + bias[o]
//   lam_g = 0.1 + 0.06*g, g in [0,16)
// GEMM view: M=4096, N=256, K=8192 (k = s*4096 + i*16 + g).
//
// Session lessons baked in:
//  - R0's 2-barrier schedule is the best measured; occupancy/dbuf/in-reg-A all
//    null or worse (R1/R2/R5). In-kernel cross-XCD fences/atomics cost ~+30us
//    (R6/R7): keep the separate reduce dispatch (dispatch boundary = free fence).
//  - Remaining removable cost is TRAFFIC: split-K P round-trip.
// This version: SPLITK 8->4 implemented as BK=128 (NOT 2x iters, which was
// R3's regression): 16 iterations, same barrier count, same total B-staging
// (128 MiB), same per-iter structure with 4 MFMA k-steps; P halves to 16 MiB.
// Tiling: BM=128, BN=128, BK=128, 256 threads (2x2 waves of 64x64), SPLITK=4
// -> grid 32x2x4 = 256 blocks. LDS 66.5 KB.
// ---------------------------------------------------------------------------

typedef __bf16 bf16x8 __attribute__((ext_vector_type(8)));
typedef __bf16 bf16x4 __attribute__((ext_vector_type(4)));
typedef float  f32x4  __attribute__((ext_vector_type(4)));

#define M_TOT 4096
#define N_TOT 256
#define MN_TOT (M_TOT * N_TOT)
#define SPLITK 4

__device__ __forceinline__ void gload_lds16(const __bf16* g, __bf16* l) {
  // async 16B/lane global->LDS; LDS dest = wave-uniform base + lane*16
  __builtin_amdgcn_global_load_lds(
      (const __attribute__((address_space(1))) void*)g,
      (__attribute__((address_space(3))) void*)l, 16, 0, 0);
}

// fp32 coeffs (2,O,I,G) -> bf16 Wb[o][k], k = s*4096 + i*16 + g.
// Both sides contiguous over x=(i*16+g) for fixed (s,o): pure chunk copy+cvt.
__global__ void convert_w(const float* __restrict__ C, __bf16* __restrict__ W) {
  int t = blockIdx.x * 256 + threadIdx.x;      // 524288 threads, 4 elems each
  int E = t << 2;
  int c = E >> 12, x4 = E & 4095;              // c = s*256+o
  int s = c >> 8, o = c & 255;
  const f32x4 v = *(const f32x4*)(C + (size_t)c * 4096 + x4);
  bf16x4 w;
  w[0] = (__bf16)v[0]; w[1] = (__bf16)v[1]; w[2] = (__bf16)v[2]; w[3] = (__bf16)v[3];
  *(bf16x4*)(W + (size_t)o * 8192 + (size_t)s * 4096 + x4) = w;
}

// MODE 0: write split-K partials to P.  MODE 1: atomicAdd into Out (+bias at kt==0).
template <int MODE>
__global__ __launch_bounds__(256, 2)
void laplace_gemm(const float* __restrict__ X, const __bf16* __restrict__ Wb,
                  const float* __restrict__ Bias, float* __restrict__ Out,
                  float* __restrict__ P) {
  // A tile 128 rows x 128 k, padded to 136 elem/row (272B: 16B-aligned)
  __shared__ __bf16 As[128 * 136];
  // B tile 128 rows x 128 k, rows 256B; 16B chunks XOR-swizzled by (row&7)
  __shared__ __bf16 Bs[128 * 128];

  const int tid = threadIdx.x;
  const int mt = blockIdx.x, nt = blockIdx.y, kt = blockIdx.z;
  const int m0 = mt * 128, n0 = nt * 128;
  const int s   = kt >> 1;          // sign half: 0 -> exp(-e), 1 -> exp(+e)
  const int i0c = (kt & 1) * 128;   // i-range of this K-chunk (128 i values)

  const int wv = tid >> 6, lane = tid & 63;
  const int wm = wv & 1, wn = wv >> 1;    // 2x2 wave grid, each 64x64
  const int lm = lane & 15, q = lane >> 4;

  // A-gen: 1024 (row, i-sub) pairs/iter; thread t, pair u: row = u*32+(t>>3),
  // isub = t&7 (8 i-values per iter at BK=128)
  const int rr0 = tid >> 3, isub = tid & 7;
  const float* xrow[4];
#pragma unroll
  for (int u = 0; u < 4; ++u)
    xrow[u] = X + (size_t)(m0 + u * 32 + rr0) * 256 + i0c + isub;

  const float sgn = s ? 1.0f : -1.0f;
  const float c0 = 0.1f * sgn, cd = 0.06f * sgn;

  const f32x4 zero = {0.f, 0.f, 0.f, 0.f};
  f32x4 acc[4][4];
#pragma unroll
  for (int a = 0; a < 4; ++a)
#pragma unroll
    for (int b = 0; b < 4; ++b) acc[a][b] = zero;

  // element offset of this K-chunk within a Wb row
  const size_t wrow = (size_t)s * 4096 + (size_t)i0c * 16;

  float xc[4];
#pragma unroll
  for (int u = 0; u < 4; ++u) xc[u] = *xrow[u];

  for (int j = 0; j < 16; ++j) {   // 16 x BK=128 -> K-chunk 2048
    // ---- async stage B tile (8 x 16B per thread = 32 KB) ----
    const size_t kw = wrow + (size_t)j * 128;
#pragma unroll
    for (int qq = 0; qq < 8; ++qq) {
      const int idx = qq * 256 + tid;
      const int r = idx >> 4, cc = idx & 15;
      const __bf16* gsrc = Wb + (size_t)(n0 + r) * 8192 + kw + ((cc ^ (r & 7)) << 3);
      __bf16* ldst = Bs + ((qq * 256 + (tid & ~63)) << 3);  // wave-uniform base
      gload_lds16(gsrc, ldst);
    }

    // prefetch next iter's x while loads are in flight
    float xn[4] = {0.f, 0.f, 0.f, 0.f};
    if (j < 15) {
#pragma unroll
      for (int u = 0; u < 4; ++u) xn[u] = xrow[u][8 * (j + 1)];
    }

    // ---- generate A features: f_g = p * r^g (4 pairs/thread) ----
#pragma unroll
    for (int u = 0; u < 4; ++u) {
      const float p0 = __expf(c0 * xc[u]), rr = __expf(cd * xc[u]);
      bf16x8 v0, v1; float f = p0;
#pragma unroll
      for (int h = 0; h < 8; ++h) { v0[h] = (__bf16)f; f *= rr; }
#pragma unroll
      for (int h = 0; h < 8; ++h) { v1[h] = (__bf16)f; f *= rr; }
      const int ro = (u * 32 + rr0) * 136 + isub * 16;
      *(bf16x8*)&As[ro]     = v0;
      *(bf16x8*)&As[ro + 8] = v1;
    }

    __syncthreads();   // drains vmcnt (B tile) + lgkm (A writes)

    // ---- MFMA: 4 k-steps x 4x4 frags ----
#pragma unroll
    for (int kk = 0; kk < 4; ++kk) {
      bf16x8 af[4], bfr[4];
#pragma unroll
      for (int a = 0; a < 4; ++a)
        af[a] = *(const bf16x8*)&As[(wm * 64 + a * 16 + lm) * 136 + kk * 32 + q * 8];
      const int pc8 = (((kk << 2) + q) ^ (lm & 7)) << 3;  // un-swizzle B chunk
#pragma unroll
      for (int b = 0; b < 4; ++b)
        bfr[b] = *(const bf16x8*)&Bs[(wn * 64 + b * 16 + lm) * 128 + pc8];
#pragma unroll
      for (int a = 0; a < 4; ++a)
#pragma unroll
        for (int b = 0; b < 4; ++b)
          acc[a][b] = __builtin_amdgcn_mfma_f32_16x16x32_bf16(af[a], bfr[b], acc[a][b], 0, 0, 0);
    }
    __syncthreads();   // before next iter overwrites tiles

#pragma unroll
    for (int u = 0; u < 4; ++u) xc[u] = xn[u];
  }

  // ---- epilogue: D[row=q*4+reg][col=lm] (m89-verified C/D layout) ----
  if constexpr (MODE == 0) {
    float* Pk = P + (size_t)kt * MN_TOT;
#pragma unroll
    for (int a = 0; a < 4; ++a) {
      const int mrow = m0 + wm * 64 + a * 16 + q * 4;
#pragma unroll
      for (int rr = 0; rr < 4; ++rr)
#pragma unroll
        for (int b = 0; b < 4; ++b) {
          const int n = n0 + wn * 64 + b * 16 + lm;
          Pk[(size_t)(mrow + rr) * 256 + n] = acc[a][b][rr];
        }
    }
  } else {
#pragma unroll
    for (int a = 0; a < 4; ++a) {
      const int mrow = m0 + wm * 64 + a * 16 + q * 4;
#pragma unroll
      for (int rr = 0; rr < 4; ++rr)
#pragma unroll
        for (int b = 0; b < 4; ++b) {
          const int n = n0 + wn * 64 + b * 16 + lm;
          float v = acc[a][b][rr];
          if (kt == 0) v += Bias[n];
          atomicAdd(&Out[(size_t)(mrow + rr) * 256 + n], v);
        }
    }
  }
}

// sum 4 split-K partials + bias -> out
__global__ void reduce_bias(const float* __restrict__ P, const float* __restrict__ Bias,
                            float* __restrict__ Out) {
  const int t = blockIdx.x * 256 + threadIdx.x;
  const size_t base = (size_t)t * 4;
  f32x4 sv = *(const f32x4*)&P[base];
#pragma unroll
  for (int k = 1; k < SPLITK; ++k) sv += *(const f32x4*)&P[(size_t)k * MN_TOT + base];
  sv += *(const f32x4*)&Bias[base & 255];
  *(f32x4*)&Out[base] = sv;
}

extern "C" void kernel_launch(void* const* d_in, const int* in_sizes, int n_in,
                              void* d_out, int out_size, void* d_ws, size_t ws_size,
                              hipStream_t stream) {
  const float* X    = (const float*)d_in[0];
  const float* C    = (const float*)d_in[1];
  const float* Bias = (const float*)d_in[2];
  float* Out = (float*)d_out;

  __bf16* Wb = (__bf16*)d_ws;
  const size_t wb_bytes = (size_t)N_TOT * 8192 * sizeof(__bf16);   // 4 MiB
  const size_t p_bytes  = (size_t)SPLITK * MN_TOT * sizeof(float); // 16 MiB
  float* P = (float*)((char*)d_ws + wb_bytes);

  convert_w<<<2048, 256, 0, stream>>>(C, Wb);

  if (ws_size >= wb_bytes + p_bytes) {
    laplace_gemm<0><<<dim3(32, 2, SPLITK), 256, 0, stream>>>(X, Wb, Bias, Out, P);
    reduce_bias<<<1024, 256, 0, stream>>>(P, Bias, Out);
  } else {
    hipMemsetAsync(d_out, 0, (size_t)out_size * sizeof(float), stream);
    laplace_gemm<1><<<dim3(32, 2, SPLITK), 256, 0, stream>>>(X, Wb, Bias, Out, P);
  }
}

// Round 9
// 93.002 us; speedup vs baseline: 1.3372x; 1.0777x over previous
//
#include <hip/hip_runtime.h>

// ---------------------------------------------------------------------------
// LaplaceKAN layer as a fused-feature bf16 MFMA GEMM.
//   y[b,o] = sum_{i,g} exp(-x[b,i]*lam_g)*C[0,o,i,g] + exp(+x[b,i]*lam_g)*C[1,o,i,g] + bias[o]
//   lam_g = 0.1 + 0.06*g, g in [0,16)
// GEMM view: M=4096, N=256, K=8192 (k = s*4096 + i*16 + g), A generated on the
// fly from x via p*r^g recurrence (2 exp + 15 mul per 16 features), B = coeffs
// pre-cast to bf16 in workspace with natural [o][k] (B^T) layout.
// Tiling: BM=128, BN=128, BK=64, 256 threads (2x2 waves of 64x64), splitK=8
// -> 512 blocks = 2 blocks/CU so gen-VALU overlaps MFMA across waves.
//
// SESSION-FINAL (R0-R8): this exact configuration measured best (91.9us).
// Empirical model: wall = 16 iters x tau(BK); tau minimized at BK=64.
// Tested and rejected: occupancy 4/CU (R1 null), in-reg A-gen (R2 -2.5),
// SPLITK4 via 2x iters (R3 -11), dbuf+1-barrier (R5 -1.8), atomic epilogue
// (R6 -32), in-kernel ticket reduce (R7 -29), SPLITK4 via BK128 (R8 -8).
// ---------------------------------------------------------------------------

typedef __bf16 bf16x8 __attribute__((ext_vector_type(8)));
typedef __bf16 bf16x4 __attribute__((ext_vector_type(4)));
typedef float  f32x4  __attribute__((ext_vector_type(4)));

#define M_TOT 4096
#define N_TOT 256
#define MN_TOT (M_TOT * N_TOT)
#define SPLITK 8

__device__ __forceinline__ void gload_lds16(const __bf16* g, __bf16* l) {
  // async 16B/lane global->LDS; LDS dest = wave-uniform base + lane*16
  __builtin_amdgcn_global_load_lds(
      (const __attribute__((address_space(1))) void*)g,
      (__attribute__((address_space(3))) void*)l, 16, 0, 0);
}

// fp32 coeffs (2,O,I,G) -> bf16 Wb[o][k], k = s*4096 + i*16 + g.
// Both sides contiguous over x=(i*16+g) for fixed (s,o): pure chunk copy+cvt.
__global__ void convert_w(const float* __restrict__ C, __bf16* __restrict__ W) {
  int t = blockIdx.x * 256 + threadIdx.x;      // 524288 threads, 4 elems each
  int E = t << 2;
  int c = E >> 12, x4 = E & 4095;              // c = s*256+o
  int s = c >> 8, o = c & 255;
  const f32x4 v = *(const f32x4*)(C + (size_t)c * 4096 + x4);
  bf16x4 w;
  w[0] = (__bf16)v[0]; w[1] = (__bf16)v[1]; w[2] = (__bf16)v[2]; w[3] = (__bf16)v[3];
  *(bf16x4*)(W + (size_t)o * 8192 + (size_t)s * 4096 + x4) = w;
}

// MODE 0: write split-K partials to P.  MODE 1: atomicAdd into Out (+bias at kt==0).
template <int MODE>
__global__ __launch_bounds__(256, 2)
void laplace_gemm(const float* __restrict__ X, const __bf16* __restrict__ Wb,
                  const float* __restrict__ Bias, float* __restrict__ Out,
                  float* __restrict__ P) {
  // A tile padded to 72 elem/row (144B: 16B-aligned, bank-balanced reads/writes)
  __shared__ __bf16 As[128 * 72];
  // B tile 128x64, rows 128B; 16B chunks XOR-swizzled by (row&7) for bank spread
  __shared__ __bf16 Bs[128 * 64];

  const int tid = threadIdx.x;
  const int mt = blockIdx.x, nt = blockIdx.y, kt = blockIdx.z;
  const int m0 = mt * 128, n0 = nt * 128;
  const int s   = kt >> 2;          // sign half: 0 -> exp(-e), 1 -> exp(+e)
  const int i0c = (kt & 3) * 64;    // i-range of this K-chunk (64 i values)

  const int wv = tid >> 6, lane = tid & 63;
  const int wm = wv & 1, wn = wv >> 1;    // 2x2 wave grid, each 64x64
  const int lm = lane & 15, q = lane >> 4;

  // feature-gen assignment: thread handles two (row, i-sub) pairs per iter
  const int mr0 = tid >> 2,         ii0 = tid & 3;
  const int mr1 = (256 + tid) >> 2, ii1 = tid & 3;   // (256+tid)&3 == tid&3
  const float* xp0 = X + (size_t)(m0 + mr0) * 256 + i0c + ii0;
  const float* xp1 = X + (size_t)(m0 + mr1) * 256 + i0c + ii1;

  const float sgn = s ? 1.0f : -1.0f;
  const float c0 = 0.1f * sgn, cd = 0.06f * sgn;

  const f32x4 zero = {0.f, 0.f, 0.f, 0.f};
  f32x4 acc[4][4];
#pragma unroll
  for (int a = 0; a < 4; ++a)
#pragma unroll
    for (int b = 0; b < 4; ++b) acc[a][b] = zero;

  // element offset of this K-chunk within a Wb row
  const size_t wrow = (size_t)s * 4096 + (size_t)i0c * 16;

  float xc0 = *xp0, xc1 = *xp1;

  for (int j = 0; j < 16; ++j) {   // 16 x BK=64 -> K-chunk 1024
    // ---- async stage B tile (4 x 16B per thread) ----
    const size_t kw = wrow + (size_t)j * 64;
#pragma unroll
    for (int qq = 0; qq < 4; ++qq) {
      const int idx = qq * 256 + tid;
      const int r = idx >> 3, cc = idx & 7;
      const __bf16* gsrc = Wb + (size_t)(n0 + r) * 8192 + kw + ((cc ^ (r & 7)) << 3);
      __bf16* ldst = Bs + ((qq * 256 + (tid & ~63)) << 3);  // wave-uniform base
      gload_lds16(gsrc, ldst);
    }

    // prefetch next iter's x while loads are in flight
    float xn0 = 0.f, xn1 = 0.f;
    if (j < 15) { xn0 = xp0[4 * (j + 1)]; xn1 = xp1[4 * (j + 1)]; }

    // ---- generate A features: f_g = p * r^g ----
    {
      const float p0 = __expf(c0 * xc0), rr = __expf(cd * xc0);
      bf16x8 v0, v1; float f = p0;
#pragma unroll
      for (int h = 0; h < 8; ++h) { v0[h] = (__bf16)f; f *= rr; }
#pragma unroll
      for (int h = 0; h < 8; ++h) { v1[h] = (__bf16)f; f *= rr; }
      *(bf16x8*)&As[mr0 * 72 + ii0 * 16]     = v0;
      *(bf16x8*)&As[mr0 * 72 + ii0 * 16 + 8] = v1;
    }
    {
      const float p0 = __expf(c0 * xc1), rr = __expf(cd * xc1);
      bf16x8 v0, v1; float f = p0;
#pragma unroll
      for (int h = 0; h < 8; ++h) { v0[h] = (__bf16)f; f *= rr; }
#pragma unroll
      for (int h = 0; h < 8; ++h) { v1[h] = (__bf16)f; f *= rr; }
      *(bf16x8*)&As[mr1 * 72 + ii1 * 16]     = v0;
      *(bf16x8*)&As[mr1 * 72 + ii1 * 16 + 8] = v1;
    }

    __syncthreads();   // drains vmcnt (B tile) + lgkm (A writes)

    // ---- MFMA: 2 k-steps x 4x4 frags ----
#pragma unroll
    for (int kk = 0; kk < 2; ++kk) {
      bf16x8 af[4], bf[4];
#pragma unroll
      for (int a = 0; a < 4; ++a)
        af[a] = *(const bf16x8*)&As[(wm * 64 + a * 16 + lm) * 72 + kk * 32 + q * 8];
      const int pc8 = (((kk << 2) + q) ^ (lm & 7)) << 3;  // un-swizzle B chunk
#pragma unroll
      for (int b = 0; b < 4; ++b)
        bf[b] = *(const bf16x8*)&Bs[(wn * 64 + b * 16 + lm) * 64 + pc8];
#pragma unroll
      for (int a = 0; a < 4; ++a)
#pragma unroll
        for (int b = 0; b < 4; ++b)
          acc[a][b] = __builtin_amdgcn_mfma_f32_16x16x32_bf16(af[a], bf[b], acc[a][b], 0, 0, 0);
    }
    __syncthreads();   // before next iter overwrites tiles

    xc0 = xn0; xc1 = xn1;
  }

  // ---- epilogue: D[row=q*4+reg][col=lm] (m89-verified C/D layout) ----
  if constexpr (MODE == 0) {
    float* Pk = P + (size_t)kt * MN_TOT;
#pragma unroll
    for (int a = 0; a < 4; ++a) {
      const int mrow = m0 + wm * 64 + a * 16 + q * 4;
#pragma unroll
      for (int rr = 0; rr < 4; ++rr)
#pragma unroll
        for (int b = 0; b < 4; ++b) {
          const int n = n0 + wn * 64 + b * 16 + lm;
          Pk[(size_t)(mrow + rr) * 256 + n] = acc[a][b][rr];
        }
    }
  } else {
#pragma unroll
    for (int a = 0; a < 4; ++a) {
      const int mrow = m0 + wm * 64 + a * 16 + q * 4;
#pragma unroll
      for (int rr = 0; rr < 4; ++rr)
#pragma unroll
        for (int b = 0; b < 4; ++b) {
          const int n = n0 + wn * 64 + b * 16 + lm;
          float v = acc[a][b][rr];
          if (kt == 0) v += Bias[n];
          atomicAdd(&Out[(size_t)(mrow + rr) * 256 + n], v);
        }
    }
  }
}

// sum 8 split-K partials + bias -> out
__global__ void reduce_bias(const float* __restrict__ P, const float* __restrict__ Bias,
                            float* __restrict__ Out) {
  const int t = blockIdx.x * 256 + threadIdx.x;
  const size_t base = (size_t)t * 4;
  f32x4 sv = *(const f32x4*)&P[base];
#pragma unroll
  for (int k = 1; k < SPLITK; ++k) sv += *(const f32x4*)&P[(size_t)k * MN_TOT + base];
  sv += *(const f32x4*)&Bias[base & 255];
  *(f32x4*)&Out[base] = sv;
}

extern "C" void kernel_launch(void* const* d_in, const int* in_sizes, int n_in,
                              void* d_out, int out_size, void* d_ws, size_t ws_size,
                              hipStream_t stream) {
  const float* X    = (const float*)d_in[0];
  const float* C    = (const float*)d_in[1];
  const float* Bias = (const float*)d_in[2];
  float* Out = (float*)d_out;

  __bf16* Wb = (__bf16*)d_ws;
  const size_t wb_bytes = (size_t)N_TOT * 8192 * sizeof(__bf16);   // 4 MiB
  const size_t p_bytes  = (size_t)SPLITK * MN_TOT * sizeof(float); // 32 MiB
  float* P = (float*)((char*)d_ws + wb_bytes);

  convert_w<<<2048, 256, 0, stream>>>(C, Wb);

  if (ws_size >= wb_bytes + p_bytes) {
    laplace_gemm<0><<<dim3(32, 2, SPLITK), 256, 0, stream>>>(X, Wb, Bias, Out, P);
    reduce_bias<<<1024, 256, 0, stream>>>(P, Bias, Out);
  } else {
    hipMemsetAsync(d_out, 0, (size_t)out_size * sizeof(float), stream);
    laplace_gemm<1><<<dim3(32, 2, SPLITK), 256, 0, stream>>>(X, Wb, Bias, Out, P);
  }
}